// Round 9
// baseline (285.454 us; speedup 1.0000x reference)
//
#include <hip/hip_runtime.h>
#include <hip/hip_cooperative_groups.h>
#include <cstdint>
#include <cstddef>

namespace cg = cooperative_groups;

// Problem constants (SparseLinear: B=4096, IN=4096, OUT=4096, NNZ=1677722)
#define IN_F  4096
#define OUT_F 4096
#define BATCH 4096

typedef __bf16 bf16_t;
typedef __bf16 bf16x8 __attribute__((ext_vector_type(8)));
typedef float  f32x4  __attribute__((ext_vector_type(4)));

#define WU16   ((OUT_F * IN_F) / 8)   // 16B units of Wbf (2097152)
#define XUNITS ((BATCH * IN_F) / 8)   // 8-elem units of x (2097152)
#define NTHR   (256 * 512)            // fused grid: 131072 threads

// ---------------------------------------------------------------------------
// f32 -> bf16 round-to-nearest-even (bit trick, deterministic)
// ---------------------------------------------------------------------------
__device__ __forceinline__ unsigned short f32_to_bf16_rne(float f) {
  union { float f; unsigned int u; } v;
  v.f = f;
  unsigned int u = v.u;
  return (unsigned short)((u + 0x7FFFu + ((u >> 16) & 1u)) >> 16);
}

__device__ __forceinline__ uint4 cvt8(float4 a, float4 b) {
  uint4 o;
  o.x = (unsigned)f32_to_bf16_rne(a.x) | ((unsigned)f32_to_bf16_rne(a.y) << 16);
  o.y = (unsigned)f32_to_bf16_rne(a.z) | ((unsigned)f32_to_bf16_rne(a.w) << 16);
  o.z = (unsigned)f32_to_bf16_rne(b.x) | ((unsigned)f32_to_bf16_rne(b.y) << 16);
  o.w = (unsigned)f32_to_bf16_rne(b.z) | ((unsigned)f32_to_bf16_rne(b.w) << 16);
  return o;
}

// ---------------------------------------------------------------------------
// GEMM phase helpers (R4-proven 8-phase schedule, 0 bank conflicts)
// LDS per tile: [ks(2)][256 rows][32 cols] bf16; 64B rows = 4 x 16B slots.
// Read swizzle: slot = c ^ ((row>>1)&3)  (decorrelated from bank-half bit).
// Write side: thread tid stages LDS linearly at tid*16 from GLOBAL chunk
// (tid&3) ^ ((srow>>1)&3); (srow+128) keeps the same value (bit7 stripped).
// ---------------------------------------------------------------------------
#define A0_B 0
#define B0_B 32768
#define A1_B 65536
#define B1_B 98304
#define HALF 16384

#define STAGE(Xg, kpos, ldsbase) do {                                          \
  __builtin_amdgcn_global_load_lds(                                            \
    (const __attribute__((address_space(1))) void*)((Xg) + (size_t)srow * 4096 + (kpos) + schunk), \
    (__attribute__((address_space(3))) void*)(lds + (ldsbase) + tid * 16), 16, 0, 0); \
  __builtin_amdgcn_global_load_lds(                                            \
    (const __attribute__((address_space(1))) void*)((Xg) + (size_t)(srow + 128) * 4096 + (kpos) + schunk), \
    (__attribute__((address_space(3))) void*)(lds + (ldsbase) + 8192 + tid * 16), 16, 0, 0); \
} while (0)

#define LDA4(base, mh) do {                                                    \
  a0 = *(const bf16x8*)(lds + (base) + offA[mh][0]);                           \
  a1 = *(const bf16x8*)(lds + (base) + offA[mh][1]);                           \
  a2 = *(const bf16x8*)(lds + (base) + offA[mh][2]);                           \
  a3 = *(const bf16x8*)(lds + (base) + offA[mh][3]);                           \
} while (0)

#define LDB4(base) do {                                                        \
  b0 = *(const bf16x8*)(lds + (base) + offB[0]);                               \
  b1 = *(const bf16x8*)(lds + (base) + offB[1]);                               \
  b2 = *(const bf16x8*)(lds + (base) + offB[2]);                               \
  b3 = *(const bf16x8*)(lds + (base) + offB[3]);                               \
} while (0)

#define MFMA16(mh) do {                                                        \
  acc[(mh)*4+0][0] = __builtin_amdgcn_mfma_f32_16x16x32_bf16(a0, b0, acc[(mh)*4+0][0], 0, 0, 0); \
  acc[(mh)*4+0][1] = __builtin_amdgcn_mfma_f32_16x16x32_bf16(a0, b1, acc[(mh)*4+0][1], 0, 0, 0); \
  acc[(mh)*4+0][2] = __builtin_amdgcn_mfma_f32_16x16x32_bf16(a0, b2, acc[(mh)*4+0][2], 0, 0, 0); \
  acc[(mh)*4+0][3] = __builtin_amdgcn_mfma_f32_16x16x32_bf16(a0, b3, acc[(mh)*4+0][3], 0, 0, 0); \
  acc[(mh)*4+1][0] = __builtin_amdgcn_mfma_f32_16x16x32_bf16(a1, b0, acc[(mh)*4+1][0], 0, 0, 0); \
  acc[(mh)*4+1][1] = __builtin_amdgcn_mfma_f32_16x16x32_bf16(a1, b1, acc[(mh)*4+1][1], 0, 0, 0); \
  acc[(mh)*4+1][2] = __builtin_amdgcn_mfma_f32_16x16x32_bf16(a1, b2, acc[(mh)*4+1][2], 0, 0, 0); \
  acc[(mh)*4+1][3] = __builtin_amdgcn_mfma_f32_16x16x32_bf16(a1, b3, acc[(mh)*4+1][3], 0, 0, 0); \
  acc[(mh)*4+2][0] = __builtin_amdgcn_mfma_f32_16x16x32_bf16(a2, b0, acc[(mh)*4+2][0], 0, 0, 0); \
  acc[(mh)*4+2][1] = __builtin_amdgcn_mfma_f32_16x16x32_bf16(a2, b1, acc[(mh)*4+2][1], 0, 0, 0); \
  acc[(mh)*4+2][2] = __builtin_amdgcn_mfma_f32_16x16x32_bf16(a2, b2, acc[(mh)*4+2][2], 0, 0, 0); \
  acc[(mh)*4+2][3] = __builtin_amdgcn_mfma_f32_16x16x32_bf16(a2, b3, acc[(mh)*4+2][3], 0, 0, 0); \
  acc[(mh)*4+3][0] = __builtin_amdgcn_mfma_f32_16x16x32_bf16(a3, b0, acc[(mh)*4+3][0], 0, 0, 0); \
  acc[(mh)*4+3][1] = __builtin_amdgcn_mfma_f32_16x16x32_bf16(a3, b1, acc[(mh)*4+3][1], 0, 0, 0); \
  acc[(mh)*4+3][2] = __builtin_amdgcn_mfma_f32_16x16x32_bf16(a3, b2, acc[(mh)*4+3][2], 0, 0, 0); \
  acc[(mh)*4+3][3] = __builtin_amdgcn_mfma_f32_16x16x32_bf16(a3, b3, acc[(mh)*4+3][3], 0, 0, 0); \
} while (0)

#define BAR()   __builtin_amdgcn_s_barrier()
#define LGKM0() do { asm volatile("s_waitcnt lgkmcnt(0)" ::: "memory");        \
                     __builtin_amdgcn_sched_barrier(0); } while (0)
#define VM(n)   asm volatile("s_waitcnt vmcnt(" #n ")" ::: "memory")
#define PRIO1() __builtin_amdgcn_s_setprio(1)
#define PRIO0() __builtin_amdgcn_s_setprio(0)

// ---------------------------------------------------------------------------
// ONE cooperative kernel: zero-W | grid.sync | scatter + cvt-x | grid.sync |
// 256x256 8-phase GEMM (R4 schedule, best measured: 116.5us, MfmaUtil 50).
// Grid = 256 blocks x 512 threads = exactly 1 block/CU (128KB LDS) -> valid
// cooperative co-residency. grid.sync() provides device-scope fences
// (cross-XCD L2 visibility for the phase handoffs).
// ---------------------------------------------------------------------------
__global__ __launch_bounds__(512, 2) void fused_all(
    const float4* __restrict__ xin, const float* __restrict__ wvals,
    const int* __restrict__ idx, const int* __restrict__ mask, int nnz,
    bf16_t* __restrict__ Wbf, bf16_t* __restrict__ xbf,
    float* __restrict__ C) {
  __shared__ __align__(16) char lds[131072];

  const int tid  = threadIdx.x;
  const int gtid = blockIdx.x * 512 + tid;

  // ---------------- Phase A: zero bf16 W (32MB, 16 uint4/thread) ----------
  {
    uint4* Wv = (uint4*)Wbf;
    const uint4 z = {0u, 0u, 0u, 0u};
#pragma unroll
    for (int r = 0; r < WU16 / NTHR; ++r)
      Wv[gtid + r * NTHR] = z;
  }
  cg::this_grid().sync();

  // ---------------- Phase B: scatter (atomics) + cvt x -> bf16 ------------
  {
    const int* rows = idx;
    const int* cols = idx + nnz;
    uint4* xv = (uint4*)xbf;
    unsigned* Wpk = (unsigned*)Wbf;
    const int total = nnz + XUNITS;
    for (int u = gtid; u < total; u += NTHR) {
      if (u < nnz) {
        if (mask[u] != 0) {
          const unsigned h = f32_to_bf16_rne(wvals[u]);
          const size_t e = (size_t)rows[u] * IN_F + cols[u];
          const unsigned data = (e & 1) ? (h << 16) : h;
          unsigned* p = Wpk + (e >> 1);
          asm volatile("global_atomic_pk_add_bf16 %0, %1, off"
                       :: "v"(p), "v"(data) : "memory");
        }
      } else {
        const int i = u - nnz;
        xv[i] = cvt8(xin[2 * i], xin[2 * i + 1]);
      }
    }
  }
  cg::this_grid().sync();

  // ---------------- Phase C: GEMM y = x @ W^T (R4 8-phase schedule) -------
  const bf16_t* A  = xbf;
  const bf16_t* Bm = Wbf;

  const int lane = tid & 63;
  const int wave = tid >> 6;
  const int wm   = wave >> 2;  // 0..1  (M half of block)
  const int wn   = wave & 3;   // 0..3  (N quarter of block)

  // T1: XCD-aware swizzle; 256 blocks % 8 == 0 -> bijective
  const int sbid = (blockIdx.x & 7) * 32 + (blockIdx.x >> 3);
  const int bm   = sbid >> 4;
  const int bn   = sbid & 15;

  const int frow = lane & 15;
  const int c16  = (lane >> 4) * 16;  // 16B chunk within 64B row

  int offA[2][4], offB[4];
#pragma unroll
  for (int mh = 0; mh < 2; ++mh)
#pragma unroll
    for (int mi = 0; mi < 4; ++mi) {
      int r = wm * 128 + mh * 64 + mi * 16 + frow;
      offA[mh][mi] = r * 64 + (c16 ^ (((r >> 1) & 3) << 4));
    }
#pragma unroll
  for (int ni = 0; ni < 4; ++ni) {
    int r = wn * 64 + ni * 16 + frow;
    offB[ni] = r * 64 + (c16 ^ (((r >> 1) & 3) << 4));
  }

  const int srow   = tid >> 2;
  const int schunk = ((tid & 3) ^ ((srow >> 1) & 3)) * 8;
  const bf16_t* Ag = A  + (size_t)bm * 256 * 4096;
  const bf16_t* Bg = Bm + (size_t)bn * 256 * 4096;

  f32x4 acc[8][4] = {};
  bf16x8 a0, a1, a2, a3, b0, b1, b2, b3;

  // prologue: tile0 (full) + tile1 ks0; drain tile0, keep tile1 in flight
  STAGE(Ag, 0,  A0_B);
  STAGE(Bg, 0,  B0_B);
  STAGE(Ag, 32, A0_B + HALF);
  STAGE(Bg, 32, B0_B + HALF);
  STAGE(Ag, 64, A1_B);
  STAGE(Bg, 64, B1_B);
  VM(4);
  BAR();

  int kb = 0;
#pragma unroll 1
  for (int i = 0; i < 31; ++i, kb += 128) {
    // ph1: tile t ks0 mh0
    LDA4(A0_B, 0); LDB4(B0_B);
    STAGE(Ag, kb + 96, A1_B + HALF);
    BAR(); LGKM0(); PRIO1(); MFMA16(0); PRIO0(); BAR();
    // ph2: tile t ks0 mh1
    LDA4(A0_B, 1);
    STAGE(Bg, kb + 96, B1_B + HALF);
    BAR(); LGKM0(); PRIO1(); MFMA16(1); PRIO0(); BAR();
    // ph3: tile t ks1 mh0
    LDA4(A0_B + HALF, 0); LDB4(B0_B + HALF);
    STAGE(Ag, kb + 128, A0_B);
    BAR(); LGKM0(); PRIO1(); MFMA16(0); PRIO0(); BAR();
    // ph4: tile t ks1 mh1   [counted drain: tile t+1 fully landed]
    LDA4(A0_B + HALF, 1);
    STAGE(Bg, kb + 128, B0_B);
    BAR(); LGKM0(); PRIO1(); MFMA16(1); PRIO0(); VM(4); BAR();
    // ph5: tile t+1 ks0 mh0
    LDA4(A1_B, 0); LDB4(B1_B);
    STAGE(Ag, kb + 160, A0_B + HALF);
    BAR(); LGKM0(); PRIO1(); MFMA16(0); PRIO0(); BAR();
    // ph6: tile t+1 ks0 mh1
    LDA4(A1_B, 1);
    STAGE(Bg, kb + 160, B0_B + HALF);
    BAR(); LGKM0(); PRIO1(); MFMA16(1); PRIO0(); BAR();
    // ph7: tile t+1 ks1 mh0
    LDA4(A1_B + HALF, 0); LDB4(B1_B + HALF);
    STAGE(Ag, kb + 192, A1_B);
    BAR(); LGKM0(); PRIO1(); MFMA16(0); PRIO0(); BAR();
    // ph8: tile t+1 ks1 mh1  [counted drain: tile t+2 fully landed]
    LDA4(A1_B + HALF, 1);
    STAGE(Bg, kb + 192, B1_B);
    BAR(); LGKM0(); PRIO1(); MFMA16(1); PRIO0(); VM(4); BAR();
  }

  // epilogue: tiles 62 (buf0) and 63 (buf1); kb == 3968
  LDA4(A0_B, 0); LDB4(B0_B);
  STAGE(Ag, kb + 96, A1_B + HALF);          // A(63)ks1
  BAR(); LGKM0(); PRIO1(); MFMA16(0); PRIO0(); BAR();
  LDA4(A0_B, 1);
  STAGE(Bg, kb + 96, B1_B + HALF);          // B(63)ks1
  BAR(); LGKM0(); PRIO1(); MFMA16(1); PRIO0(); BAR();
  LDA4(A0_B + HALF, 0); LDB4(B0_B + HALF);
  BAR(); LGKM0(); PRIO1(); MFMA16(0); PRIO0(); BAR();
  LDA4(A0_B + HALF, 1);
  BAR(); LGKM0(); PRIO1(); MFMA16(1); PRIO0(); VM(0); BAR();
  LDA4(A1_B, 0); LDB4(B1_B);
  BAR(); LGKM0(); PRIO1(); MFMA16(0); PRIO0(); BAR();
  LDA4(A1_B, 1);
  BAR(); LGKM0(); PRIO1(); MFMA16(1); PRIO0(); BAR();
  LDA4(A1_B + HALF, 0); LDB4(B1_B + HALF);
  BAR(); LGKM0(); PRIO1(); MFMA16(0); PRIO0(); BAR();
  LDA4(A1_B + HALF, 1);
  LGKM0(); PRIO1(); MFMA16(1); PRIO0();

  // C write (D layout: col = lane&15, row = (lane>>4)*4 + jj)
#pragma unroll
  for (int mh = 0; mh < 2; ++mh)
#pragma unroll
    for (int mi = 0; mi < 4; ++mi)
#pragma unroll
      for (int ni = 0; ni < 4; ++ni) {
        const int row = bm * 256 + wm * 128 + mh * 64 + mi * 16 + (lane >> 4) * 4;
        const int col = bn * 256 + wn * 64 + ni * 16 + frow;
#pragma unroll
        for (int jj = 0; jj < 4; ++jj)
          C[(size_t)(row + jj) * 4096 + col] = acc[mh * 4 + mi][ni][jj];
      }
}

// ---------------------------------------------------------------------------
extern "C" void kernel_launch(void* const* d_in, const int* in_sizes, int n_in,
                              void* d_out, int out_size, void* d_ws, size_t ws_size,
                              hipStream_t stream) {
  const float4* xin  = (const float4*)d_in[0];
  const float* wvals = (const float*)d_in[1];
  const int*   idx   = (const int*)d_in[2];   // (2, nnz): rows then cols
  const int*   mk    = (const int*)d_in[3];   // bool -> int32 on device (R1)
  int          nnz   = in_sizes[1];

  // ws: [0,32MB) = W bf16, [32MB,64MB) = x bf16.
  bf16_t* Wbf = (bf16_t*)d_ws;
  bf16_t* xbf = (bf16_t*)((char*)d_ws + (size_t)OUT_F * IN_F * sizeof(bf16_t));
  float*  Cout = (float*)d_out;

  const size_t needed = (size_t)OUT_F * IN_F * 2 + (size_t)BATCH * IN_F * 2;
  if (ws_size < needed) return;

  void* kargs[] = {(void*)&xin, (void*)&wvals, (void*)&idx, (void*)&mk,
                   (void*)&nnz, (void*)&Wbf, (void*)&xbf, (void*)&Cout};
  hipLaunchCooperativeKernel((const void*)fused_all, dim3(256), dim3(512),
                             kargs, 0, stream);
}

// Round 10
// 209.115 us; speedup vs baseline: 1.3651x; 1.3651x over previous
//
#include <hip/hip_runtime.h>
#include <cstdint>
#include <cstddef>

// Problem constants (SparseLinear: B=4096, IN=4096, OUT=4096, NNZ=1677722)
#define IN_F  4096
#define OUT_F 4096
#define BATCH 4096

typedef __bf16 bf16_t;
typedef __bf16 bf16x8 __attribute__((ext_vector_type(8)));
typedef float  f32x4  __attribute__((ext_vector_type(4)));

// ---------------------------------------------------------------------------
// f32 -> bf16 round-to-nearest-even (bit trick, deterministic)
// ---------------------------------------------------------------------------
__device__ __forceinline__ unsigned short f32_to_bf16_rne(float f) {
  union { float f; unsigned int u; } v;
  v.f = f;
  unsigned int u = v.u;
  return (unsigned short)((u + 0x7FFFu + ((u >> 16) & 1u)) >> 16);
}

__device__ __forceinline__ uint4 cvt8(float4 a, float4 b) {
  uint4 o;
  o.x = (unsigned)f32_to_bf16_rne(a.x) | ((unsigned)f32_to_bf16_rne(a.y) << 16);
  o.y = (unsigned)f32_to_bf16_rne(a.z) | ((unsigned)f32_to_bf16_rne(a.w) << 16);
  o.z = (unsigned)f32_to_bf16_rne(b.x) | ((unsigned)f32_to_bf16_rne(b.y) << 16);
  o.w = (unsigned)f32_to_bf16_rne(b.z) | ((unsigned)f32_to_bf16_rne(b.w) << 16);
  return o;
}

// ---------------------------------------------------------------------------
// Fused: zero the bf16 W buffer AND convert x -> bf16. Grid-stride, high
// occupancy (R9 lesson: do NOT run these phases at GEMM occupancy).
// ---------------------------------------------------------------------------
#define WU16   ((OUT_F * IN_F) / 8)   // 16B units of Wbf (2097152)
#define XUNITS ((BATCH * IN_F) / 8)   // 8-elem units of x (2097152)

__global__ __launch_bounds__(256) void init_zero_cvtx(
    uint4* __restrict__ Wbfv, const float4* __restrict__ xin,
    uint4* __restrict__ xbf) {
  const uint4 z = {0u, 0u, 0u, 0u};
  for (int u = blockIdx.x * 256 + threadIdx.x; u < WU16 + XUNITS;
       u += gridDim.x * 256) {
    if (u < WU16) {
      Wbfv[u] = z;
    } else {
      const int i = u - WU16;
      xbf[i] = cvt8(xin[2 * i], xin[2 * i + 1]);
    }
  }
}

// ---------------------------------------------------------------------------
// Scatter-add COO weights directly into bf16 W (packed-bf16 atomic add).
// Duplicates still sum (coalesce semantics). mask is int32 on device (R1).
// ---------------------------------------------------------------------------
__global__ __launch_bounds__(256) void scatter_bf16(
    const float* __restrict__ w, const int* __restrict__ rows,
    const int* __restrict__ cols, const int* __restrict__ mask,
    unsigned* __restrict__ Wpk, int nnz) {
  int i = blockIdx.x * 256 + threadIdx.x;
  if (i >= nnz) return;
  if (mask[i] == 0) return;
  const unsigned h = f32_to_bf16_rne(w[i]);
  const size_t e = (size_t)rows[i] * IN_F + cols[i];
  const unsigned data = (e & 1) ? (h << 16) : h;
  unsigned* p = Wpk + (e >> 1);
  asm volatile("global_atomic_pk_add_bf16 %0, %1, off"
               :: "v"(p), "v"(data) : "memory");
}

// ---------------------------------------------------------------------------
// 256x256 8-phase bf16 GEMM, C = A @ Bm^T (row-major [4096][4096]).
// R4-EXACT schedule (best measured: 116.5us, MfmaUtil 50.2, conflicts 0).
// T1 XCD swizzle + T2 decorrelated XOR swizzle + counted VM(4) at ph4/ph8
// only + T5 setprio. Structural ceiling note (R9 analysis): per wave per
// K-tile(32), 12KB LDS reads vs 524K flops = 43.7 flops/B; at the measured
// b128 LDS ceiling (~85-90 B/cy/CU) this exactly matches the MFMA pipe rate
// -> the kernel sits at the LDS-read/MFMA crossover; schedule shuffles
// (R5 deep-vmcnt, R6 4-phase, R8 readahead) were all flat-to-negative.
// ---------------------------------------------------------------------------
#define A0_B 0
#define B0_B 32768
#define A1_B 65536
#define B1_B 98304
#define HALF 16384

#define STAGE(Xg, kpos, ldsbase) do {                                          \
  __builtin_amdgcn_global_load_lds(                                            \
    (const __attribute__((address_space(1))) void*)((Xg) + (size_t)srow * 4096 + (kpos) + schunk), \
    (__attribute__((address_space(3))) void*)(lds + (ldsbase) + tid * 16), 16, 0, 0); \
  __builtin_amdgcn_global_load_lds(                                            \
    (const __attribute__((address_space(1))) void*)((Xg) + (size_t)(srow + 128) * 4096 + (kpos) + schunk), \
    (__attribute__((address_space(3))) void*)(lds + (ldsbase) + 8192 + tid * 16), 16, 0, 0); \
} while (0)

#define LDA4(base, mh) do {                                                    \
  a0 = *(const bf16x8*)(lds + (base) + offA[mh][0]);                           \
  a1 = *(const bf16x8*)(lds + (base) + offA[mh][1]);                           \
  a2 = *(const bf16x8*)(lds + (base) + offA[mh][2]);                           \
  a3 = *(const bf16x8*)(lds + (base) + offA[mh][3]);                           \
} while (0)

#define LDB4(base) do {                                                        \
  b0 = *(const bf16x8*)(lds + (base) + offB[0]);                               \
  b1 = *(const bf16x8*)(lds + (base) + offB[1]);                               \
  b2 = *(const bf16x8*)(lds + (base) + offB[2]);                               \
  b3 = *(const bf16x8*)(lds + (base) + offB[3]);                               \
} while (0)

#define MFMA16(mh) do {                                                        \
  acc[(mh)*4+0][0] = __builtin_amdgcn_mfma_f32_16x16x32_bf16(a0, b0, acc[(mh)*4+0][0], 0, 0, 0); \
  acc[(mh)*4+0][1] = __builtin_amdgcn_mfma_f32_16x16x32_bf16(a0, b1, acc[(mh)*4+0][1], 0, 0, 0); \
  acc[(mh)*4+0][2] = __builtin_amdgcn_mfma_f32_16x16x32_bf16(a0, b2, acc[(mh)*4+0][2], 0, 0, 0); \
  acc[(mh)*4+0][3] = __builtin_amdgcn_mfma_f32_16x16x32_bf16(a0, b3, acc[(mh)*4+0][3], 0, 0, 0); \
  acc[(mh)*4+1][0] = __builtin_amdgcn_mfma_f32_16x16x32_bf16(a1, b0, acc[(mh)*4+1][0], 0, 0, 0); \
  acc[(mh)*4+1][1] = __builtin_amdgcn_mfma_f32_16x16x32_bf16(a1, b1, acc[(mh)*4+1][1], 0, 0, 0); \
  acc[(mh)*4+1][2] = __builtin_amdgcn_mfma_f32_16x16x32_bf16(a1, b2, acc[(mh)*4+1][2], 0, 0, 0); \
  acc[(mh)*4+1][3] = __builtin_amdgcn_mfma_f32_16x16x32_bf16(a1, b3, acc[(mh)*4+1][3], 0, 0, 0); \
  acc[(mh)*4+2][0] = __builtin_amdgcn_mfma_f32_16x16x32_bf16(a2, b0, acc[(mh)*4+2][0], 0, 0, 0); \
  acc[(mh)*4+2][1] = __builtin_amdgcn_mfma_f32_16x16x32_bf16(a2, b1, acc[(mh)*4+2][1], 0, 0, 0); \
  acc[(mh)*4+2][2] = __builtin_amdgcn_mfma_f32_16x16x32_bf16(a2, b2, acc[(mh)*4+2][2], 0, 0, 0); \
  acc[(mh)*4+2][3] = __builtin_amdgcn_mfma_f32_16x16x32_bf16(a2, b3, acc[(mh)*4+2][3], 0, 0, 0); \
  acc[(mh)*4+3][0] = __builtin_amdgcn_mfma_f32_16x16x32_bf16(a3, b0, acc[(mh)*4+3][0], 0, 0, 0); \
  acc[(mh)*4+3][1] = __builtin_amdgcn_mfma_f32_16x16x32_bf16(a3, b1, acc[(mh)*4+3][1], 0, 0, 0); \
  acc[(mh)*4+3][2] = __builtin_amdgcn_mfma_f32_16x16x32_bf16(a3, b2, acc[(mh)*4+3][2], 0, 0, 0); \
  acc[(mh)*4+3][3] = __builtin_amdgcn_mfma_f32_16x16x32_bf16(a3, b3, acc[(mh)*4+3][3], 0, 0, 0); \
} while (0)

#define BAR()   __builtin_amdgcn_s_barrier()
#define LGKM0() do { asm volatile("s_waitcnt lgkmcnt(0)" ::: "memory");        \
                     __builtin_amdgcn_sched_barrier(0); } while (0)
#define VM(n)   asm volatile("s_waitcnt vmcnt(" #n ")" ::: "memory")
#define PRIO1() __builtin_amdgcn_s_setprio(1)
#define PRIO0() __builtin_amdgcn_s_setprio(0)

__global__ __launch_bounds__(512, 2) void gemm_bt_8ph(
    const bf16_t* __restrict__ A, const bf16_t* __restrict__ Bm,
    float* __restrict__ C) {
  __shared__ __align__(16) char lds[131072];

  const int tid  = threadIdx.x;
  const int lane = tid & 63;
  const int wave = tid >> 6;
  const int wm   = wave >> 2;  // 0..1  (M half of block)
  const int wn   = wave & 3;   // 0..3  (N quarter of block)

  // T1: XCD-aware swizzle; 256 blocks % 8 == 0 -> bijective
  const int sbid = (blockIdx.x & 7) * 32 + (blockIdx.x >> 3);
  const int bm   = sbid >> 4;
  const int bn   = sbid & 15;

  const int frow = lane & 15;
  const int c16  = (lane >> 4) * 16;  // 16B chunk within 64B row

  // ds_read byte offsets within a ks-half [256][32] region (T2-swizzled,
  // decorrelated: XOR with row bits 1-2; R4-verified 0 conflicts)
  int offA[2][4], offB[4];
#pragma unroll
  for (int mh = 0; mh < 2; ++mh)
#pragma unroll
    for (int mi = 0; mi < 4; ++mi) {
      int r = wm * 128 + mh * 64 + mi * 16 + frow;
      offA[mh][mi] = r * 64 + (c16 ^ (((r >> 1) & 3) << 4));
    }
#pragma unroll
  for (int ni = 0; ni < 4; ++ni) {
    int r = wn * 64 + ni * 16 + frow;
    offB[ni] = r * 64 + (c16 ^ (((r >> 1) & 3) << 4));
  }

  // staging: write-side inverse of the read swizzle ((srow+128) keeps the
  // same ((row>>1)&3): bit7 is stripped by &3)
  const int srow   = tid >> 2;
  const int schunk = ((tid & 3) ^ ((srow >> 1) & 3)) * 8;
  const bf16_t* Ag = A  + (size_t)bm * 256 * 4096;
  const bf16_t* Bg = Bm + (size_t)bn * 256 * 4096;

  f32x4 acc[8][4] = {};
  bf16x8 a0, a1, a2, a3, b0, b1, b2, b3;

  // ---- prologue: tile0 (full) + tile1 ks0; drain tile0, keep tile1 in flight
  STAGE(Ag, 0,  A0_B);
  STAGE(Bg, 0,  B0_B);
  STAGE(Ag, 32, A0_B + HALF);
  STAGE(Bg, 32, B0_B + HALF);
  STAGE(Ag, 64, A1_B);
  STAGE(Bg, 64, B1_B);
  VM(4);
  BAR();

  int kb = 0;
#pragma unroll 1
  for (int i = 0; i < 31; ++i, kb += 128) {
    // ph1: tile t ks0 mh0
    LDA4(A0_B, 0); LDB4(B0_B);
    STAGE(Ag, kb + 96, A1_B + HALF);
    BAR(); LGKM0(); PRIO1(); MFMA16(0); PRIO0(); BAR();
    // ph2: tile t ks0 mh1
    LDA4(A0_B, 1);
    STAGE(Bg, kb + 96, B1_B + HALF);
    BAR(); LGKM0(); PRIO1(); MFMA16(1); PRIO0(); BAR();
    // ph3: tile t ks1 mh0
    LDA4(A0_B + HALF, 0); LDB4(B0_B + HALF);
    STAGE(Ag, kb + 128, A0_B);
    BAR(); LGKM0(); PRIO1(); MFMA16(0); PRIO0(); BAR();
    // ph4: tile t ks1 mh1   [counted drain: tile t+1 fully landed]
    LDA4(A0_B + HALF, 1);
    STAGE(Bg, kb + 128, B0_B);
    BAR(); LGKM0(); PRIO1(); MFMA16(1); PRIO0(); VM(4); BAR();
    // ph5: tile t+1 ks0 mh0
    LDA4(A1_B, 0); LDB4(B1_B);
    STAGE(Ag, kb + 160, A0_B + HALF);
    BAR(); LGKM0(); PRIO1(); MFMA16(0); PRIO0(); BAR();
    // ph6: tile t+1 ks0 mh1
    LDA4(A1_B, 1);
    STAGE(Bg, kb + 160, B0_B + HALF);
    BAR(); LGKM0(); PRIO1(); MFMA16(1); PRIO0(); BAR();
    // ph7: tile t+1 ks1 mh0
    LDA4(A1_B + HALF, 0); LDB4(B1_B + HALF);
    STAGE(Ag, kb + 192, A1_B);
    BAR(); LGKM0(); PRIO1(); MFMA16(0); PRIO0(); BAR();
    // ph8: tile t+1 ks1 mh1  [counted drain: tile t+2 fully landed]
    LDA4(A1_B + HALF, 1);
    STAGE(Bg, kb + 192, B1_B);
    BAR(); LGKM0(); PRIO1(); MFMA16(1); PRIO0(); VM(4); BAR();
  }

  // ---- epilogue: tiles 62 (buf0) and 63 (buf1); kb == 3968
  LDA4(A0_B, 0); LDB4(B0_B);
  STAGE(Ag, kb + 96, A1_B + HALF);          // A(63)ks1
  BAR(); LGKM0(); PRIO1(); MFMA16(0); PRIO0(); BAR();
  LDA4(A0_B, 1);
  STAGE(Bg, kb + 96, B1_B + HALF);          // B(63)ks1
  BAR(); LGKM0(); PRIO1(); MFMA16(1); PRIO0(); BAR();
  LDA4(A0_B + HALF, 0); LDB4(B0_B + HALF);
  BAR(); LGKM0(); PRIO1(); MFMA16(0); PRIO0(); BAR();
  LDA4(A0_B + HALF, 1);
  BAR(); LGKM0(); PRIO1(); MFMA16(1); PRIO0(); VM(0); BAR();
  LDA4(A1_B, 0); LDB4(B1_B);
  BAR(); LGKM0(); PRIO1(); MFMA16(0); PRIO0(); BAR();
  LDA4(A1_B, 1);
  BAR(); LGKM0(); PRIO1(); MFMA16(1); PRIO0(); BAR();
  LDA4(A1_B + HALF, 0); LDB4(B1_B + HALF);
  BAR(); LGKM0(); PRIO1(); MFMA16(0); PRIO0(); BAR();
  LDA4(A1_B + HALF, 1);
  LGKM0(); PRIO1(); MFMA16(1); PRIO0();

  // ---- C write (D layout: col = lane&15, row = (lane>>4)*4 + jj)
#pragma unroll
  for (int mh = 0; mh < 2; ++mh)
#pragma unroll
    for (int mi = 0; mi < 4; ++mi)
#pragma unroll
      for (int ni = 0; ni < 4; ++ni) {
        const int row = bm * 256 + wm * 128 + mh * 64 + mi * 16 + (lane >> 4) * 4;
        const int col = bn * 256 + wn * 64 + ni * 16 + frow;
#pragma unroll
        for (int jj = 0; jj < 4; ++jj)
          C[(size_t)(row + jj) * 4096 + col] = acc[mh * 4 + mi][ni][jj];
      }
}

// ---------------------------------------------------------------------------
extern "C" void kernel_launch(void* const* d_in, const int* in_sizes, int n_in,
                              void* d_out, int out_size, void* d_ws, size_t ws_size,
                              hipStream_t stream) {
  const float* x     = (const float*)d_in[0];
  const float* wvals = (const float*)d_in[1];
  const int*   idx   = (const int*)d_in[2];   // (2, nnz): rows then cols
  const int*   mk    = (const int*)d_in[3];   // bool -> int32 on device (R1)
  const int    nnz   = in_sizes[1];

  // ws: [0,32MB) = W bf16, [32MB,64MB) = x bf16.
  bf16_t* Wbf = (bf16_t*)d_ws;
  bf16_t* xbf = (bf16_t*)((char*)d_ws + (size_t)OUT_F * IN_F * sizeof(bf16_t));

  const size_t needed = (size_t)OUT_F * IN_F * 2 + (size_t)BATCH * IN_F * 2;
  if (ws_size < needed) return;

  // 1. fused: zero bf16 W + convert x -> bf16 (high occupancy, R9 lesson)
  init_zero_cvtx<<<2048, 256, 0, stream>>>(
      (uint4*)Wbf, (const float4*)x, (uint4*)xbf);

  // 2. scatter-add active weights directly in bf16 (packed atomic)
  scatter_bf16<<<(nnz + 255) / 256, 256, 0, stream>>>(
      wvals, idx, idx + nnz, mk, (unsigned*)Wbf, nnz);

  // 3. y = x @ W^T (R4-exact 8-phase schedule)
  gemm_bt_8ph<<<256, 512, 0, stream>>>(xbf, Wbf, (float*)d_out);
}